// Round 1
// baseline (1093.253 us; speedup 1.0000x reference)
//
#include <hip/hip_runtime.h>
#include <cstdint>
#include <cstddef>

#define NN 50000
#define NE 800000
#define D 128
#define KK 256          // concat K dim: [h | agg]
#define NPAD 50048      // 782 * 64, node-tile padded
#define ROWS_PER_RB 256
#define RB_BLOCKS 196   // ceil(50000/256)

// ---------------- CSR build ----------------

__global__ void k_zero_i(int* __restrict__ p, int n) {
    int i = blockIdx.x * blockDim.x + threadIdx.x;
    if (i < n) p[i] = 0;
}

__global__ void k_hist(const int* __restrict__ dst, int* __restrict__ counts) {
    int e = blockIdx.x * blockDim.x + threadIdx.x;
    if (e < NE) atomicAdd(&counts[dst[e]], 1);
}

// single block, 1024 threads: exclusive scan counts[NN] -> row_ptr[NN+1]
__global__ void k_scan(const int* __restrict__ counts, int* __restrict__ row_ptr) {
    __shared__ int sums[1024];
    int t = threadIdx.x;
    const int CH = (NN + 1023) / 1024;  // 49
    int start = t * CH;
    int end = min(start + CH, NN);
    int s = 0;
    for (int i = start; i < end; i++) s += counts[i];
    sums[t] = s;
    __syncthreads();
    for (int off = 1; off < 1024; off <<= 1) {
        int v = (t >= off) ? sums[t - off] : 0;
        __syncthreads();
        sums[t] += v;
        __syncthreads();
    }
    int prefix = (t == 0) ? 0 : sums[t - 1];
    for (int i = start; i < end; i++) { row_ptr[i] = prefix; prefix += counts[i]; }
    if (t == 1023) row_ptr[NN] = sums[1023];
}

__global__ void k_fill(const int* __restrict__ src, const int* __restrict__ dst,
                       const int* __restrict__ row_ptr, int* __restrict__ fill,
                       int* __restrict__ esrc) {
    int e = blockIdx.x * blockDim.x + threadIdx.x;
    if (e < NE) {
        int d = dst[e];
        int p = atomicAdd(&fill[d], 1);
        esrc[row_ptr[d] + p] = src[e];
    }
}

// pack W2[l][j][0:128]=Vw[l][j][:], W2[l][j][128:256]=Aw[l][j][:]
__global__ void k_packw(const float* __restrict__ Vw, const float* __restrict__ Aw,
                        float* __restrict__ W2) {
    int idx = blockIdx.x * blockDim.x + threadIdx.x;
    if (idx >= 3 * D * KK) return;
    int k = idx & (KK - 1);
    int j = (idx >> 8) & (D - 1);
    int l = idx >> 15;
    float v = (k < D) ? Vw[((size_t)l * D + j) * D + k]
                      : Aw[((size_t)l * D + j) * D + (k - D)];
    W2[idx] = v;
}

// ---------------- per-layer ----------------

// column partial sums: block = 128 threads (1 col each), ROWS_PER_RB rows
__global__ void k_readout(const float* __restrict__ h, float* __restrict__ part) {
    int col = threadIdx.x;
    int r0 = blockIdx.x * ROWS_PER_RB;
    int r1 = min(r0 + ROWS_PER_RB, NN);
    float s = 0.f;
    for (int i = r0; i < r1; i++) s += h[(size_t)i * D + col];
    part[blockIdx.x * D + col] = s;
}

// rbias[j] = Vb[j]+Ab[j]+Rb[j] + sum_k ro[k]*Rw[j][k]
__global__ void k_rbias(const float* __restrict__ part, const float* __restrict__ Rw,
                        const float* __restrict__ Vb, const float* __restrict__ Ab,
                        const float* __restrict__ Rb, float* __restrict__ rbias) {
    __shared__ float sro[D];
    int j = threadIdx.x;
    float s = 0.f;
    for (int b = 0; b < RB_BLOCKS; b++) s += part[b * D + j];
    sro[j] = s;
    __syncthreads();
    float r = Vb[j] + Ab[j] + Rb[j];
    for (int k = 0; k < D; k++) r += sro[k] * Rw[(size_t)j * D + k];
    rbias[j] = r;
}

// one wave per node: A2[i][0:128] = h[i], A2[i][128:256] = h[i] + sum_{src->i} h[src]
__global__ void k_agg(const float* __restrict__ h, const int* __restrict__ row_ptr,
                      const int* __restrict__ esrc, float* __restrict__ A2) {
    int wave = (blockIdx.x * blockDim.x + threadIdx.x) >> 6;
    int lane = threadIdx.x & 63;
    if (wave >= NN) return;
    const float2* hrow = (const float2*)(h + (size_t)wave * D);
    float2 self = hrow[lane];
    float2 acc = self;
    int b = row_ptr[wave], e2 = row_ptr[wave + 1];
    for (int e = b; e < e2; e++) {
        int s = esrc[e];
        const float2* sr = (const float2*)(h + (size_t)s * D);
        float2 v = sr[lane];
        acc.x += v.x;
        acc.y += v.y;
    }
    float2* out = (float2*)(A2 + (size_t)wave * KK);
    out[lane] = self;
    out[64 + lane] = acc;
}

// C[NPAD x 128] = relu(A2[NPAD x 256] @ W2[128 x 256]^T + rbias)
// block 256 threads: 64 nodes x 128 cols; thread = 8 nodes x 4 cols
__global__ void __launch_bounds__(256) k_gemm(const float* __restrict__ A2,
                                              const float* __restrict__ W2,
                                              const float* __restrict__ rbias,
                                              float* __restrict__ hout) {
    __shared__ float sA[64 * KK];  // 64 KB
    int n0 = blockIdx.x * 64;
    const float4* g = (const float4*)(A2 + (size_t)n0 * KK);
    float4* l4 = (float4*)sA;
#pragma unroll
    for (int i = 0; i < 16; i++) l4[threadIdx.x + 256 * i] = g[threadIdx.x + 256 * i];
    __syncthreads();

    int jg = threadIdx.x & 31, j0 = jg * 4;
    int ng = threadIdx.x >> 5;  // 0..7 -> nodes ng*8 .. ng*8+7
    float acc[8][4];
#pragma unroll
    for (int n = 0; n < 8; n++)
#pragma unroll
        for (int j = 0; j < 4; j++) acc[n][j] = 0.f;

    const float* wbase = W2 + (size_t)j0 * KK;
    for (int k = 0; k < KK; k += 4) {
        float4 b0 = *(const float4*)(wbase + k);
        float4 b1 = *(const float4*)(wbase + KK + k);
        float4 b2 = *(const float4*)(wbase + 2 * KK + k);
        float4 b3 = *(const float4*)(wbase + 3 * KK + k);
#pragma unroll
        for (int n = 0; n < 8; n++) {
            float4 a = *(const float4*)(sA + (ng * 8 + n) * KK + k);
            acc[n][0] = fmaf(a.x, b0.x, fmaf(a.y, b0.y, fmaf(a.z, b0.z, fmaf(a.w, b0.w, acc[n][0]))));
            acc[n][1] = fmaf(a.x, b1.x, fmaf(a.y, b1.y, fmaf(a.z, b1.z, fmaf(a.w, b1.w, acc[n][1]))));
            acc[n][2] = fmaf(a.x, b2.x, fmaf(a.y, b2.y, fmaf(a.z, b2.z, fmaf(a.w, b2.w, acc[n][2]))));
            acc[n][3] = fmaf(a.x, b3.x, fmaf(a.y, b3.y, fmaf(a.z, b3.z, fmaf(a.w, b3.w, acc[n][3]))));
        }
    }

    float4 rb = *(const float4*)(rbias + j0);
#pragma unroll
    for (int n = 0; n < 8; n++) {
        int row = n0 + ng * 8 + n;
        if (row < NN) {
            float4 o;
            o.x = fmaxf(acc[n][0] + rb.x, 0.f);
            o.y = fmaxf(acc[n][1] + rb.y, 0.f);
            o.z = fmaxf(acc[n][2] + rb.z, 0.f);
            o.w = fmaxf(acc[n][3] + rb.w, 0.f);
            *(float4*)(hout + (size_t)row * D + j0) = o;
        }
    }
}

// out[i][o] = sigmoid(dot(h[i], out_w[o]) + out_b[o]); one wave per node
__global__ void k_out(const float* __restrict__ h, const float* __restrict__ ow,
                      const float* __restrict__ ob, float* __restrict__ out) {
    int wave = (blockIdx.x * blockDim.x + threadIdx.x) >> 6;
    int lane = threadIdx.x & 63;
    if (wave >= NN) return;
    const float2* hr = (const float2*)(h + (size_t)wave * D);
    float2 v = hr[lane];
    const float2* w0 = (const float2*)(ow);
    const float2* w1 = (const float2*)(ow + D);
    float2 a0 = w0[lane], a1 = w1[lane];
    float p0 = v.x * a0.x + v.y * a0.y;
    float p1 = v.x * a1.x + v.y * a1.y;
    for (int off = 32; off; off >>= 1) {
        p0 += __shfl_xor(p0, off);
        p1 += __shfl_xor(p1, off);
    }
    if (lane == 0) {
        float l0 = p0 + ob[0];
        float l1 = p1 + ob[1];
        out[(size_t)wave * 2 + 0] = 1.f / (1.f + expf(-l0));
        out[(size_t)wave * 2 + 1] = 1.f / (1.f + expf(-l1));
    }
}

extern "C" void kernel_launch(void* const* d_in, const int* in_sizes, int n_in,
                              void* d_out, int out_size, void* d_ws, size_t ws_size,
                              hipStream_t stream) {
    const float* x  = (const float*)d_in[0];
    const int*   src = (const int*)d_in[1];
    const int*   dst = (const int*)d_in[2];
    const float* Vw = (const float*)d_in[3];
    const float* Vb = (const float*)d_in[4];
    const float* Aw = (const float*)d_in[5];
    const float* Ab = (const float*)d_in[6];
    const float* Rw = (const float*)d_in[7];
    const float* Rb = (const float*)d_in[8];
    const float* ow = (const float*)d_in[9];
    const float* ob = (const float*)d_in[10];
    float* out = (float*)d_out;

    char* w = (char*)d_ws;
    float* A2     = (float*)w; w += (size_t)NPAD * KK * 4;   // 51.2 MB
    float* h      = (float*)w; w += (size_t)NPAD * D * 4;    // 25.6 MB
    float* W2     = (float*)w; w += (size_t)3 * D * KK * 4;  // 384 KB
    int*   counts = (int*)w;   w += (size_t)NN * 4;          // fill must follow counts
    int*   fill   = (int*)w;   w += (size_t)NN * 4;
    int*   row_ptr= (int*)w;   w += (size_t)(NN + 4) * 4;
    int*   esrc   = (int*)w;   w += (size_t)NE * 4;
    float* part   = (float*)w; w += (size_t)RB_BLOCKS * D * 4;
    float* rbias  = (float*)w; w += (size_t)D * 4;

    // CSR build (once; reused by all 3 layers) + weight packing
    k_zero_i<<<(2 * NN + 255) / 256, 256, 0, stream>>>(counts, 2 * NN);  // counts+fill
    k_hist<<<(NE + 255) / 256, 256, 0, stream>>>(dst, counts);
    k_scan<<<1, 1024, 0, stream>>>(counts, row_ptr);
    k_fill<<<(NE + 255) / 256, 256, 0, stream>>>(src, dst, row_ptr, fill, esrc);
    k_packw<<<(3 * D * KK + 255) / 256, 256, 0, stream>>>(Vw, Aw, W2);

    const float* hcur = x;
    for (int l = 0; l < 3; l++) {
        k_readout<<<RB_BLOCKS, D, 0, stream>>>(hcur, part);
        k_rbias<<<1, D, 0, stream>>>(part, Rw + (size_t)l * D * D, Vb + (size_t)l * D,
                                     Ab + (size_t)l * D, Rb + (size_t)l * D, rbias);
        k_agg<<<NN / 4, 256, 0, stream>>>(hcur, row_ptr, esrc, A2);
        k_gemm<<<NPAD / 64, 256, 0, stream>>>(A2, W2 + (size_t)l * D * KK, rbias, h);
        hcur = h;
    }
    k_out<<<(NN * 64 + 255) / 256, 256, 0, stream>>>(h, ow, ob, out);
}

// Round 2
// 510.717 us; speedup vs baseline: 2.1406x; 2.1406x over previous
//
#include <hip/hip_runtime.h>
#include <cstdint>
#include <cstddef>

#define NN 50000
#define NE 800000
#define D 128
#define KK 256          // concat K dim: [h | agg]
#define NPAD 50048      // 391 * 128
#define LDSW 136        // tile row stride (bf16 elems): 272 B, 16B-aligned

typedef __bf16 bf16x8 __attribute__((ext_vector_type(8)));
typedef float f32x4 __attribute__((ext_vector_type(4)));
typedef unsigned short ushort;
typedef unsigned int uint;

__device__ __forceinline__ ushort f2b(float f) {
    uint u = __float_as_uint(f);
    uint r = (u + 0x7fffu + ((u >> 16) & 1u)) >> 16;
    return (ushort)r;
}
__device__ __forceinline__ float blo(uint u) { return __uint_as_float(u << 16); }
__device__ __forceinline__ float bhi(uint u) { return __uint_as_float(u & 0xffff0000u); }

// ---------------- CSR build ----------------

__global__ void k_zero_i(int* __restrict__ p, int n) {
    int i = blockIdx.x * blockDim.x + threadIdx.x;
    if (i < n) p[i] = 0;
}

__global__ void k_hist(const int* __restrict__ dst, int* __restrict__ counts) {
    int e = blockIdx.x * blockDim.x + threadIdx.x;
    if (e < NE) atomicAdd(&counts[dst[e]], 1);
}

// single block, 1024 threads: exclusive scan counts[NN] -> row_ptr[NN+1]
__global__ void k_scan(const int* __restrict__ counts, int* __restrict__ row_ptr) {
    __shared__ int sums[1024];
    int t = threadIdx.x;
    const int CH = (NN + 1023) / 1024;  // 49
    int start = t * CH;
    int end = min(start + CH, NN);
    int s = 0;
    for (int i = start; i < end; i++) s += counts[i];
    sums[t] = s;
    __syncthreads();
    for (int off = 1; off < 1024; off <<= 1) {
        int v = (t >= off) ? sums[t - off] : 0;
        __syncthreads();
        sums[t] += v;
        __syncthreads();
    }
    int prefix = (t == 0) ? 0 : sums[t - 1];
    for (int i = start; i < end; i++) { row_ptr[i] = prefix; prefix += counts[i]; }
    if (t == 1023) row_ptr[NN] = sums[1023];
}

__global__ void k_fill(const int* __restrict__ src, const int* __restrict__ dst,
                       const int* __restrict__ row_ptr, int* __restrict__ fill,
                       int* __restrict__ esrc) {
    int e = blockIdx.x * blockDim.x + threadIdx.x;
    if (e < NE) {
        int d = dst[e];
        int p = atomicAdd(&fill[d], 1);
        esrc[row_ptr[d] + p] = src[e];
    }
}

// pack W2b[l][j][0:128]=Vw[l][j][:], W2b[l][j][128:256]=Aw[l][j][:]  (bf16)
__global__ void k_packw(const float* __restrict__ Vw, const float* __restrict__ Aw,
                        ushort* __restrict__ W2) {
    int idx = blockIdx.x * blockDim.x + threadIdx.x;
    if (idx >= 3 * D * KK) return;
    int k = idx & (KK - 1);
    int j = (idx >> 8) & (D - 1);
    int l = idx >> 15;
    float v = (k < D) ? Vw[((size_t)l * D + j) * D + k]
                      : Aw[((size_t)l * D + j) * D + (k - D)];
    W2[idx] = f2b(v);
}

// convert x fp32 -> hb bf16, fused column-sum partials -> ro0 (fp32 atomics)
__global__ void k_cvt_rsum(const float* __restrict__ x, ushort* __restrict__ hb,
                           float* __restrict__ ro0) {
    int col = threadIdx.x;  // 128
    int r0 = blockIdx.x * 64;
    int r1 = min(r0 + 64, NN);
    float s = 0.f;
    for (int r = r0; r < r1; r++) {
        float v = x[(size_t)r * D + col];
        s += v;
        hb[(size_t)r * D + col] = f2b(v);
    }
    atomicAdd(&ro0[col], s);
}

// rbias[j] = Vb[j]+Ab[j]+Rb[j] + sum_k ro[k]*Rw[j][k]
__global__ void k_rbias(const float* __restrict__ ro, const float* __restrict__ Rw,
                        const float* __restrict__ Vb, const float* __restrict__ Ab,
                        const float* __restrict__ Rb, float* __restrict__ rbias) {
    __shared__ float sro[D];
    int j = threadIdx.x;
    sro[j] = ro[j];
    __syncthreads();
    float r = Vb[j] + Ab[j] + Rb[j];
    for (int k = 0; k < D; k++) r += sro[k] * Rw[(size_t)j * D + k];
    rbias[j] = r;
}

// one wave per node: A2[i][0:128] = h[i], A2[i][128:256] = h[i] + sum h[src]
// bf16 rows (256 B): lane reads one packed uint (2 bf16). Edge loop unroll-4.
__global__ void k_agg(const ushort* __restrict__ hb, const int* __restrict__ row_ptr,
                      const int* __restrict__ esrc, ushort* __restrict__ A2) {
    int wave = (blockIdx.x * blockDim.x + threadIdx.x) >> 6;
    int lane = threadIdx.x & 63;
    if (wave >= NPAD) return;
    uint* out = (uint*)(A2 + (size_t)wave * KK);
    if (wave >= NN) { out[lane] = 0u; out[64 + lane] = 0u; return; }
    const uint* hrow = (const uint*)(hb + (size_t)wave * D);
    uint su = hrow[lane];
    float ax = blo(su), ay = bhi(su);
    int b = row_ptr[wave], e2 = row_ptr[wave + 1];
    int e = b;
    float a0x = 0, a0y = 0, a1x = 0, a1y = 0, a2x = 0, a2y = 0, a3x = 0, a3y = 0;
    for (; e + 4 <= e2; e += 4) {
        int s0 = esrc[e], s1 = esrc[e + 1], s2 = esrc[e + 2], s3 = esrc[e + 3];
        uint u0 = ((const uint*)(hb + (size_t)s0 * D))[lane];
        uint u1 = ((const uint*)(hb + (size_t)s1 * D))[lane];
        uint u2 = ((const uint*)(hb + (size_t)s2 * D))[lane];
        uint u3 = ((const uint*)(hb + (size_t)s3 * D))[lane];
        a0x += blo(u0); a0y += bhi(u0);
        a1x += blo(u1); a1y += bhi(u1);
        a2x += blo(u2); a2y += bhi(u2);
        a3x += blo(u3); a3y += bhi(u3);
    }
    for (; e < e2; e++) {
        int s = esrc[e];
        uint u = ((const uint*)(hb + (size_t)s * D))[lane];
        a0x += blo(u); a0y += bhi(u);
    }
    ax += (a0x + a1x) + (a2x + a3x);
    ay += (a0y + a1y) + (a2y + a3y);
    out[lane] = su;  // exact self bits
    out[64 + lane] = (uint)f2b(ax) | ((uint)f2b(ay) << 16);
}

// hb[NPADx128] = relu(A2[NPADx256] @ W2[128x256]^T + rbias), bf16 MFMA.
// Block = 4 waves x 32 nodes = 128 nodes, all 128 cols. Fused colsum -> ro_next.
__global__ void __launch_bounds__(256) k_gemm(const ushort* __restrict__ A2,
                                              const ushort* __restrict__ W2,
                                              const float* __restrict__ rbias,
                                              ushort* __restrict__ hout,
                                              float* __restrict__ ro_next) {
    __shared__ ushort tile[4][32 * LDSW];
    __shared__ float scol[D];
    int t = threadIdx.x;
    if (t < D) scol[t] = 0.f;
    __syncthreads();

    int wave = t >> 6, lane = t & 63;
    int m = lane & 15, q = lane >> 4;
    int node0 = blockIdx.x * 128 + wave * 32;

    f32x4 acc[2][8];
#pragma unroll
    for (int a = 0; a < 2; a++)
#pragma unroll
        for (int j = 0; j < 8; j++) acc[a][j] = (f32x4){0.f, 0.f, 0.f, 0.f};

    const ushort* arow0 = A2 + (size_t)(node0 + m) * KK + q * 8;
    const ushort* arow1 = arow0 + 16 * KK;
    const ushort* brow = W2 + (size_t)m * KK + q * 8;
#pragma unroll
    for (int kt = 0; kt < 8; kt++) {
        int k0 = kt * 32;
        bf16x8 a0 = *(const bf16x8*)(arow0 + k0);
        bf16x8 a1 = *(const bf16x8*)(arow1 + k0);
#pragma unroll
        for (int j = 0; j < 8; j++) {
            bf16x8 b = *(const bf16x8*)(brow + (size_t)j * 16 * KK + k0);
            acc[0][j] = __builtin_amdgcn_mfma_f32_16x16x32_bf16(a0, b, acc[0][j], 0, 0, 0);
            acc[1][j] = __builtin_amdgcn_mfma_f32_16x16x32_bf16(a1, b, acc[1][j], 0, 0, 0);
        }
    }

    // epilogue: +rbias, relu, colsum partials, LDS transpose
    float rb[8];
#pragma unroll
    for (int j = 0; j < 8; j++) rb[j] = rbias[j * 16 + m];
    ushort* mytile = tile[wave];
    float psum[8] = {0, 0, 0, 0, 0, 0, 0, 0};
#pragma unroll
    for (int tt = 0; tt < 2; tt++)
#pragma unroll
        for (int j = 0; j < 8; j++) {
            f32x4 v = acc[tt][j];
#pragma unroll
            for (int r = 0; r < 4; r++) {
                int row = tt * 16 + q * 4 + r;  // C/D: col=lane&15, row=quad*4+reg
                float val = fmaxf(v[r] + rb[j], 0.f);
                if (node0 + row < NN) psum[j] += val;
                mytile[row * LDSW + j * 16 + m] = f2b(val);
            }
        }
#pragma unroll
    for (int j = 0; j < 8; j++) atomicAdd(&scol[j * 16 + m], psum[j]);

    // coalesced write-out (wave-private tile; in-wave lgkm ordering suffices)
#pragma unroll
    for (int it = 0; it < 8; it++) {
        int row = it * 4 + q;
        int grow = node0 + row;
        uint4 vv = *(const uint4*)(mytile + row * LDSW + m * 8);
        if (grow < NN) *(uint4*)(hout + (size_t)grow * D + m * 8) = vv;
    }
    __syncthreads();
    if (t < D) atomicAdd(&ro_next[t], scol[t]);
}

// out[i][o] = sigmoid(dot(h[i], out_w[o]) + out_b[o]); one wave per node
__global__ void k_out(const ushort* __restrict__ hb, const float* __restrict__ ow,
                      const float* __restrict__ ob, float* __restrict__ out) {
    int wave = (blockIdx.x * blockDim.x + threadIdx.x) >> 6;
    int lane = threadIdx.x & 63;
    if (wave >= NN) return;
    const uint* hr = (const uint*)(hb + (size_t)wave * D);
    uint u = hr[lane];
    float vx = blo(u), vy = bhi(u);
    const float2* w0 = (const float2*)(ow);
    const float2* w1 = (const float2*)(ow + D);
    float2 a0 = w0[lane], a1 = w1[lane];
    float p0 = vx * a0.x + vy * a0.y;
    float p1 = vx * a1.x + vy * a1.y;
    for (int off = 32; off; off >>= 1) {
        p0 += __shfl_xor(p0, off);
        p1 += __shfl_xor(p1, off);
    }
    if (lane == 0) {
        float l0 = p0 + ob[0];
        float l1 = p1 + ob[1];
        out[(size_t)wave * 2 + 0] = 1.f / (1.f + expf(-l0));
        out[(size_t)wave * 2 + 1] = 1.f / (1.f + expf(-l1));
    }
}

extern "C" void kernel_launch(void* const* d_in, const int* in_sizes, int n_in,
                              void* d_out, int out_size, void* d_ws, size_t ws_size,
                              hipStream_t stream) {
    const float* x   = (const float*)d_in[0];
    const int*   src = (const int*)d_in[1];
    const int*   dst = (const int*)d_in[2];
    const float* Vw  = (const float*)d_in[3];
    const float* Vb  = (const float*)d_in[4];
    const float* Aw  = (const float*)d_in[5];
    const float* Ab  = (const float*)d_in[6];
    const float* Rw  = (const float*)d_in[7];
    const float* Rb  = (const float*)d_in[8];
    const float* ow  = (const float*)d_in[9];
    const float* ob  = (const float*)d_in[10];
    float* out = (float*)d_out;

    char* w = (char*)d_ws;
    ushort* A2     = (ushort*)w; w += (size_t)NPAD * KK * 2;    // 25.6 MB
    ushort* hb     = (ushort*)w; w += (size_t)NPAD * D * 2;     // 12.8 MB
    ushort* W2     = (ushort*)w; w += (size_t)3 * D * KK * 2;   // 192 KB
    int*    counts = (int*)w;    w += (size_t)NN * 4;           // contiguous with fill+ro
    int*    fill   = (int*)w;    w += (size_t)NN * 4;
    float*  ro     = (float*)w;  w += (size_t)4 * D * 4;        // ro[0..3][128]
    int*    row_ptr= (int*)w;    w += (size_t)(NN + 4) * 4;
    int*    esrc   = (int*)w;    w += (size_t)NE * 4;
    float*  rbias  = (float*)w;  w += (size_t)D * 4;

    // zero counts + fill + ro in one pass (contiguous)
    k_zero_i<<<(2 * NN + 4 * D + 255) / 256, 256, 0, stream>>>(counts, 2 * NN + 4 * D);
    k_hist<<<(NE + 255) / 256, 256, 0, stream>>>(dst, counts);
    k_scan<<<1, 1024, 0, stream>>>(counts, row_ptr);
    k_fill<<<(NE + 255) / 256, 256, 0, stream>>>(src, dst, row_ptr, fill, esrc);
    k_packw<<<(3 * D * KK + 255) / 256, 256, 0, stream>>>(Vw, Aw, W2);
    k_cvt_rsum<<<(NN + 63) / 64, D, 0, stream>>>(x, hb, ro);

    for (int l = 0; l < 3; l++) {
        k_rbias<<<1, D, 0, stream>>>(ro + (size_t)l * D, Rw + (size_t)l * D * D,
                                     Vb + (size_t)l * D, Ab + (size_t)l * D,
                                     Rb + (size_t)l * D, rbias);
        k_agg<<<NPAD / 4, 256, 0, stream>>>(hb, row_ptr, esrc, A2);
        k_gemm<<<NPAD / 128, 256, 0, stream>>>(A2, W2 + (size_t)l * D * KK, rbias, hb,
                                               ro + (size_t)(l + 1) * D);
    }
    k_out<<<(NN * 64 + 255) / 256, 256, 0, stream>>>(hb, ow, ob, out);
}

// Round 3
// 449.191 us; speedup vs baseline: 2.4338x; 1.1370x over previous
//
#include <hip/hip_runtime.h>
#include <cstdint>
#include <cstddef>

#define NN 50000
#define NE 800000
#define D 128
#define KK 256          // concat K dim: [h | agg]
#define NPAD 50048      // 391 * 128
#define LDSW 136        // tile row stride (bf16 elems): 272 B, 16B-aligned
#define SCAN_BLOCKS 196 // ceil(50000/256)

typedef __bf16 bf16x8 __attribute__((ext_vector_type(8)));
typedef float f32x4 __attribute__((ext_vector_type(4)));
typedef unsigned short ushort;
typedef unsigned int uint;

__device__ __forceinline__ ushort f2b(float f) {
    uint u = __float_as_uint(f);
    uint r = (u + 0x7fffu + ((u >> 16) & 1u)) >> 16;
    return (ushort)r;
}
__device__ __forceinline__ float blo(uint u) { return __uint_as_float(u << 16); }
__device__ __forceinline__ float bhi(uint u) { return __uint_as_float(u & 0xffff0000u); }

// ---------------- CSR build ----------------

__global__ void k_zero_i(int* __restrict__ p, int n) {
    int i = blockIdx.x * blockDim.x + threadIdx.x;
    if (i < n) p[i] = 0;
}

__global__ void k_hist(const int* __restrict__ dst, int* __restrict__ counts) {
    int e = blockIdx.x * blockDim.x + threadIdx.x;
    if (e < NE) atomicAdd(&counts[dst[e]], 1);
}

// phase 1: per-block sum of 256 counts
__global__ void k_scan1(const int* __restrict__ counts, int* __restrict__ bsum) {
    int i = blockIdx.x * 256 + threadIdx.x;
    int c = (i < NN) ? counts[i] : 0;
#pragma unroll
    for (int off = 32; off; off >>= 1) c += __shfl_xor(c, off);
    __shared__ int ws[4];
    if ((threadIdx.x & 63) == 0) ws[threadIdx.x >> 6] = c;
    __syncthreads();
    if (threadIdx.x == 0) bsum[blockIdx.x] = ws[0] + ws[1] + ws[2] + ws[3];
}

// phase 2: single small block scans the 196 block sums -> exclusive offsets
__global__ void k_scan2(const int* __restrict__ bsum, int* __restrict__ boff) {
    __shared__ int s[256];
    int t = threadIdx.x;
    int v = (t < SCAN_BLOCKS) ? bsum[t] : 0;
    s[t] = v;
    __syncthreads();
    for (int off = 1; off < 256; off <<= 1) {
        int u = (t >= off) ? s[t - off] : 0;
        __syncthreads();
        s[t] += u;
        __syncthreads();
    }
    if (t < SCAN_BLOCKS) boff[t] = (t == 0) ? 0 : s[t - 1];
}

// phase 3: per-block exclusive scan + offset -> row_ptr (incl. row_ptr[NN])
__global__ void k_scan3(const int* __restrict__ counts, const int* __restrict__ boff,
                        int* __restrict__ row_ptr) {
    __shared__ int s[256];
    int t = threadIdx.x;
    int i = blockIdx.x * 256 + t;
    int c = (i < NN) ? counts[i] : 0;
    s[t] = c;
    __syncthreads();
    for (int off = 1; off < 256; off <<= 1) {
        int u = (t >= off) ? s[t - off] : 0;
        __syncthreads();
        s[t] += u;
        __syncthreads();
    }
    if (i <= NN) row_ptr[i] = boff[blockIdx.x] + s[t] - c;
}

__global__ void k_fill(const int* __restrict__ src, const int* __restrict__ dst,
                       const int* __restrict__ row_ptr, int* __restrict__ fill,
                       int* __restrict__ esrc) {
    int e = blockIdx.x * blockDim.x + threadIdx.x;
    if (e < NE) {
        int d = dst[e];
        int p = atomicAdd(&fill[d], 1);
        esrc[row_ptr[d] + p] = src[e];
    }
}

// pack W2b[l][j][0:128]=Vw[l][j][:], W2b[l][j][128:256]=Aw[l][j][:]  (bf16)
__global__ void k_packw(const float* __restrict__ Vw, const float* __restrict__ Aw,
                        ushort* __restrict__ W2) {
    int idx = blockIdx.x * blockDim.x + threadIdx.x;
    if (idx >= 3 * D * KK) return;
    int k = idx & (KK - 1);
    int j = (idx >> 8) & (D - 1);
    int l = idx >> 15;
    float v = (k < D) ? Vw[((size_t)l * D + j) * D + k]
                      : Aw[((size_t)l * D + j) * D + (k - D)];
    W2[idx] = f2b(v);
}

// convert x fp32 -> hb bf16, fused column-sum partials -> ro0 (fp32 atomics)
__global__ void k_cvt_rsum(const float* __restrict__ x, ushort* __restrict__ hb,
                           float* __restrict__ ro0) {
    int col = threadIdx.x;  // 128
    int r0 = blockIdx.x * 64;
    int r1 = min(r0 + 64, NN);
    float s = 0.f;
    for (int r = r0; r < r1; r++) {
        float v = x[(size_t)r * D + col];
        s += v;
        hb[(size_t)r * D + col] = f2b(v);
    }
    atomicAdd(&ro0[col], s);
}

// rbias[j] = Vb[j]+Ab[j]+Rb[j] + sum_k ro[k]*Rw[j][k]
__global__ void k_rbias(const float* __restrict__ ro, const float* __restrict__ Rw,
                        const float* __restrict__ Vb, const float* __restrict__ Ab,
                        const float* __restrict__ Rb, float* __restrict__ rbias) {
    __shared__ float sro[D];
    int j = threadIdx.x;
    sro[j] = ro[j];
    __syncthreads();
    float r = Vb[j] + Ab[j] + Rb[j];
    for (int k = 0; k < D; k++) r += sro[k] * Rw[(size_t)j * D + k];
    rbias[j] = r;
}

// one wave per node: A2[i][0:128] = h[i], A2[i][128:256] = h[i] + sum h[src]
__global__ void k_agg(const ushort* __restrict__ hb, const int* __restrict__ row_ptr,
                      const int* __restrict__ esrc, ushort* __restrict__ A2) {
    int wave = (blockIdx.x * blockDim.x + threadIdx.x) >> 6;
    int lane = threadIdx.x & 63;
    if (wave >= NPAD) return;
    uint* out = (uint*)(A2 + (size_t)wave * KK);
    if (wave >= NN) { out[lane] = 0u; out[64 + lane] = 0u; return; }
    const uint* hrow = (const uint*)(hb + (size_t)wave * D);
    uint su = hrow[lane];
    float ax = blo(su), ay = bhi(su);
    int b = row_ptr[wave], e2 = row_ptr[wave + 1];
    int e = b;
    float a0x = 0, a0y = 0, a1x = 0, a1y = 0, a2x = 0, a2y = 0, a3x = 0, a3y = 0;
    for (; e + 4 <= e2; e += 4) {
        int s0 = esrc[e], s1 = esrc[e + 1], s2 = esrc[e + 2], s3 = esrc[e + 3];
        uint u0 = ((const uint*)(hb + (size_t)s0 * D))[lane];
        uint u1 = ((const uint*)(hb + (size_t)s1 * D))[lane];
        uint u2 = ((const uint*)(hb + (size_t)s2 * D))[lane];
        uint u3 = ((const uint*)(hb + (size_t)s3 * D))[lane];
        a0x += blo(u0); a0y += bhi(u0);
        a1x += blo(u1); a1y += bhi(u1);
        a2x += blo(u2); a2y += bhi(u2);
        a3x += blo(u3); a3y += bhi(u3);
    }
    for (; e < e2; e++) {
        int s = esrc[e];
        uint u = ((const uint*)(hb + (size_t)s * D))[lane];
        a0x += blo(u); a0y += bhi(u);
    }
    ax += (a0x + a1x) + (a2x + a3x);
    ay += (a0y + a1y) + (a2y + a3y);
    out[lane] = su;  // exact self bits
    out[64 + lane] = (uint)f2b(ax) | ((uint)f2b(ay) << 16);
}

// hb[NPADx128] = relu(A2[NPADx256] @ W2[128x256]^T + rbias), bf16 MFMA.
// Block = 4 waves x 32 nodes = 128 nodes, all 128 cols. Fused colsum -> ro_next.
__global__ void __launch_bounds__(256) k_gemm(const ushort* __restrict__ A2,
                                              const ushort* __restrict__ W2,
                                              const float* __restrict__ rbias,
                                              ushort* __restrict__ hout,
                                              float* __restrict__ ro_next) {
    __shared__ ushort tile[4][32 * LDSW];
    __shared__ float scol[D];
    int t = threadIdx.x;
    if (t < D) scol[t] = 0.f;
    __syncthreads();

    int wave = t >> 6, lane = t & 63;
    int m = lane & 15, q = lane >> 4;
    int node0 = blockIdx.x * 128 + wave * 32;

    f32x4 acc[2][8];
#pragma unroll
    for (int a = 0; a < 2; a++)
#pragma unroll
        for (int j = 0; j < 8; j++) acc[a][j] = (f32x4){0.f, 0.f, 0.f, 0.f};

    const ushort* arow0 = A2 + (size_t)(node0 + m) * KK + q * 8;
    const ushort* arow1 = arow0 + 16 * KK;
    const ushort* brow = W2 + (size_t)m * KK + q * 8;
#pragma unroll
    for (int kt = 0; kt < 8; kt++) {
        int k0 = kt * 32;
        bf16x8 a0 = *(const bf16x8*)(arow0 + k0);
        bf16x8 a1 = *(const bf16x8*)(arow1 + k0);
#pragma unroll
        for (int j = 0; j < 8; j++) {
            bf16x8 b = *(const bf16x8*)(brow + (size_t)j * 16 * KK + k0);
            acc[0][j] = __builtin_amdgcn_mfma_f32_16x16x32_bf16(a0, b, acc[0][j], 0, 0, 0);
            acc[1][j] = __builtin_amdgcn_mfma_f32_16x16x32_bf16(a1, b, acc[1][j], 0, 0, 0);
        }
    }

    // epilogue: +rbias, relu, colsum partials, LDS transpose
    float rb[8];
#pragma unroll
    for (int j = 0; j < 8; j++) rb[j] = rbias[j * 16 + m];
    ushort* mytile = tile[wave];
    float psum[8] = {0, 0, 0, 0, 0, 0, 0, 0};
#pragma unroll
    for (int tt = 0; tt < 2; tt++)
#pragma unroll
        for (int j = 0; j < 8; j++) {
            f32x4 v = acc[tt][j];
#pragma unroll
            for (int r = 0; r < 4; r++) {
                int row = tt * 16 + q * 4 + r;  // C/D: col=lane&15, row=quad*4+reg
                float val = fmaxf(v[r] + rb[j], 0.f);
                if (node0 + row < NN) psum[j] += val;
                mytile[row * LDSW + j * 16 + m] = f2b(val);
            }
        }
#pragma unroll
    for (int j = 0; j < 8; j++) atomicAdd(&scol[j * 16 + m], psum[j]);

    // coalesced write-out (wave-private tile; in-wave lgkm ordering suffices)
#pragma unroll
    for (int it = 0; it < 8; it++) {
        int row = it * 4 + q;
        int grow = node0 + row;
        uint4 vv = *(const uint4*)(mytile + row * LDSW + m * 8);
        if (grow < NN) *(uint4*)(hout + (size_t)grow * D + m * 8) = vv;
    }
    __syncthreads();
    if (t < D) atomicAdd(&ro_next[t], scol[t]);
}

// out[i][o] = sigmoid(dot(h[i], out_w[o]) + out_b[o]); one wave per node
__global__ void k_out(const ushort* __restrict__ hb, const float* __restrict__ ow,
                      const float* __restrict__ ob, float* __restrict__ out) {
    int wave = (blockIdx.x * blockDim.x + threadIdx.x) >> 6;
    int lane = threadIdx.x & 63;
    if (wave >= NN) return;
    const uint* hr = (const uint*)(hb + (size_t)wave * D);
    uint u = hr[lane];
    float vx = blo(u), vy = bhi(u);
    const float2* w0 = (const float2*)(ow);
    const float2* w1 = (const float2*)(ow + D);
    float2 a0 = w0[lane], a1 = w1[lane];
    float p0 = vx * a0.x + vy * a0.y;
    float p1 = vx * a1.x + vy * a1.y;
    for (int off = 32; off; off >>= 1) {
        p0 += __shfl_xor(p0, off);
        p1 += __shfl_xor(p1, off);
    }
    if (lane == 0) {
        float l0 = p0 + ob[0];
        float l1 = p1 + ob[1];
        out[(size_t)wave * 2 + 0] = 1.f / (1.f + expf(-l0));
        out[(size_t)wave * 2 + 1] = 1.f / (1.f + expf(-l1));
    }
}

extern "C" void kernel_launch(void* const* d_in, const int* in_sizes, int n_in,
                              void* d_out, int out_size, void* d_ws, size_t ws_size,
                              hipStream_t stream) {
    const float* x   = (const float*)d_in[0];
    const int*   src = (const int*)d_in[1];
    const int*   dst = (const int*)d_in[2];
    const float* Vw  = (const float*)d_in[3];
    const float* Vb  = (const float*)d_in[4];
    const float* Aw  = (const float*)d_in[5];
    const float* Ab  = (const float*)d_in[6];
    const float* Rw  = (const float*)d_in[7];
    const float* Rb  = (const float*)d_in[8];
    const float* ow  = (const float*)d_in[9];
    const float* ob  = (const float*)d_in[10];
    float* out = (float*)d_out;

    char* w = (char*)d_ws;
    ushort* A2     = (ushort*)w; w += (size_t)NPAD * KK * 2;    // 25.6 MB
    ushort* hb     = (ushort*)w; w += (size_t)NPAD * D * 2;     // 12.8 MB
    ushort* W2     = (ushort*)w; w += (size_t)3 * D * KK * 2;   // 192 KB
    int*    counts = (int*)w;    w += (size_t)NN * 4;           // contiguous with fill+ro
    int*    fill   = (int*)w;    w += (size_t)NN * 4;
    float*  ro     = (float*)w;  w += (size_t)4 * D * 4;        // ro[0..3][128]
    int*    row_ptr= (int*)w;    w += (size_t)(NN + 4) * 4;
    int*    esrc   = (int*)w;    w += (size_t)NE * 4;
    float*  rbias  = (float*)w;  w += (size_t)D * 4;
    int*    bsum   = (int*)w;    w += (size_t)256 * 4;
    int*    boff   = (int*)w;    w += (size_t)256 * 4;

    // zero counts + fill + ro in one pass (contiguous)
    k_zero_i<<<(2 * NN + 4 * D + 255) / 256, 256, 0, stream>>>(counts, 2 * NN + 4 * D);
    k_hist<<<(NE + 255) / 256, 256, 0, stream>>>(dst, counts);
    k_scan1<<<SCAN_BLOCKS, 256, 0, stream>>>(counts, bsum);
    k_scan2<<<1, 256, 0, stream>>>(bsum, boff);
    k_scan3<<<SCAN_BLOCKS, 256, 0, stream>>>(counts, boff, row_ptr);
    k_fill<<<(NE + 255) / 256, 256, 0, stream>>>(src, dst, row_ptr, fill, esrc);
    k_packw<<<(3 * D * KK + 255) / 256, 256, 0, stream>>>(Vw, Aw, W2);
    k_cvt_rsum<<<(NN + 63) / 64, D, 0, stream>>>(x, hb, ro);

    for (int l = 0; l < 3; l++) {
        k_rbias<<<1, D, 0, stream>>>(ro + (size_t)l * D, Rw + (size_t)l * D * D,
                                     Vb + (size_t)l * D, Ab + (size_t)l * D,
                                     Rb + (size_t)l * D, rbias);
        k_agg<<<NPAD / 4, 256, 0, stream>>>(hb, row_ptr, esrc, A2);
        k_gemm<<<NPAD / 128, 256, 0, stream>>>(A2, W2 + (size_t)l * D * KK, rbias, hb,
                                               ro + (size_t)(l + 1) * D);
    }
    k_out<<<(NN * 64 + 255) / 256, 256, 0, stream>>>(hb, ow, ob, out);
}

// Round 4
// 412.087 us; speedup vs baseline: 2.6530x; 1.0900x over previous
//
#include <hip/hip_runtime.h>
#include <cstdint>
#include <cstddef>

#define NN 50000
#define NE 800000
#define D 128
#define KK 256          // concat K dim: [h | agg]
#define NPAD 50048      // 391 * 128
#define LDSW 136        // tile row stride (bf16 elems): 272 B, 16B-aligned
#define NBUCK 196       // ceil(50000/256) coarse dst buckets (256 nodes each)
#define ECH 8192        // edges per block in bucket passes
#define EBLKS ((NE + ECH - 1) / ECH)  // 98

typedef __bf16 bf16x8 __attribute__((ext_vector_type(8)));
typedef float f32x4 __attribute__((ext_vector_type(4)));
typedef unsigned short ushort;
typedef unsigned int uint;

__device__ __forceinline__ ushort f2b(float f) {
    uint u = __float_as_uint(f);
    uint r = (u + 0x7fffu + ((u >> 16) & 1u)) >> 16;
    return (ushort)r;
}
__device__ __forceinline__ float blo(uint u) { return __uint_as_float(u << 16); }
__device__ __forceinline__ float bhi(uint u) { return __uint_as_float(u & 0xffff0000u); }

// ---------------- CSR build (two-level bucket) ----------------

__global__ void k_zero_i(int* __restrict__ p, int n) {
    int i = blockIdx.x * blockDim.x + threadIdx.x;
    if (i < n) p[i] = 0;
}

// coarse histogram over 196 buckets, LDS-aggregated
__global__ void k_bhist(const int* __restrict__ dst, int* __restrict__ bcnt) {
    __shared__ int cnt[NBUCK];
    int t = threadIdx.x;
    if (t < NBUCK) cnt[t] = 0;
    __syncthreads();
    int e0 = blockIdx.x * ECH, e1 = min(e0 + ECH, NE);
    for (int e = e0 + t; e < e1; e += 256) atomicAdd(&cnt[dst[e] >> 8], 1);
    __syncthreads();
    if (t < NBUCK && cnt[t]) atomicAdd(&bcnt[t], cnt[t]);
}

// single block: exclusive scan of bucket counts -> boff[0..NBUCK], init bfill
__global__ void k_bscan(const int* __restrict__ bcnt, int* __restrict__ boff,
                        int* __restrict__ bfill) {
    __shared__ int s[256];
    int t = threadIdx.x;
    int v = (t < NBUCK) ? bcnt[t] : 0;
    s[t] = v;
    __syncthreads();
    for (int off = 1; off < 256; off <<= 1) {
        int u = (t >= off) ? s[t - off] : 0;
        __syncthreads();
        s[t] += u;
        __syncthreads();
    }
    int excl = s[t] - v;
    if (t < NBUCK) { boff[t] = excl; bfill[t] = excl; }
    if (t == 255) boff[NBUCK] = s[255];  // = NE
}

// scatter packed edges (src | (dst&255)<<16) into bucket-grouped runs.
// One reservation atomic per (block,bucket); writes are contiguous runs.
__global__ void k_bscat(const int* __restrict__ src, const int* __restrict__ dst,
                        int* __restrict__ bfill, uint* __restrict__ packed) {
    __shared__ int cnt[NBUCK];
    __shared__ int base[NBUCK];
    int t = threadIdx.x;
    if (t < NBUCK) cnt[t] = 0;
    __syncthreads();
    int e0 = blockIdx.x * ECH, e1 = min(e0 + ECH, NE);
    for (int e = e0 + t; e < e1; e += 256) atomicAdd(&cnt[dst[e] >> 8], 1);
    __syncthreads();
    if (t < NBUCK) base[t] = cnt[t] ? atomicAdd(&bfill[t], cnt[t]) : 0;
    __syncthreads();
    for (int e = e0 + t; e < e1; e += 256) {
        int d = dst[e];
        int b = d >> 8;
        int p = atomicAdd(&base[b], 1);
        packed[p] = (uint)src[e] | ((uint)(d & 255) << 16);  // src < 2^16
    }
}

// one block per bucket: fine 256-bin hist + scan -> row_ptr + esrc scatter
// within the block's exclusively-owned contiguous esrc region.
__global__ void k_bcsr(const uint* __restrict__ packed, const int* __restrict__ boff,
                       int* __restrict__ esrc, int* __restrict__ row_ptr) {
    __shared__ int hist[256];
    __shared__ int sc[256];
    __shared__ int fill[256];
    int b = blockIdx.x, t = threadIdx.x;
    int lo = boff[b], hi = boff[b + 1], cnt = hi - lo;
    hist[t] = 0;
    __syncthreads();
    for (int i = t; i < cnt; i += 256) atomicAdd(&hist[packed[lo + i] >> 16], 1);
    __syncthreads();
    int v = hist[t];
    sc[t] = v;
    __syncthreads();
    for (int off = 1; off < 256; off <<= 1) {
        int u = (t >= off) ? sc[t - off] : 0;
        __syncthreads();
        sc[t] += u;
        __syncthreads();
    }
    int excl = sc[t] - v;
    int node = b * 256 + t;
    if (node <= NN) row_ptr[node] = lo + excl;
    fill[t] = lo + excl;
    __syncthreads();
    for (int i = t; i < cnt; i += 256) {
        uint p = packed[lo + i];
        int pos = atomicAdd(&fill[p >> 16], 1);
        esrc[pos] = (int)(p & 0xffffu);
    }
}

// ---------------- weights / readout ----------------

// pack W2b[l][j][0:128]=Vw[l][j][:], W2b[l][j][128:256]=Aw[l][j][:]  (bf16)
__global__ void k_packw(const float* __restrict__ Vw, const float* __restrict__ Aw,
                        ushort* __restrict__ W2) {
    int idx = blockIdx.x * blockDim.x + threadIdx.x;
    if (idx >= 3 * D * KK) return;
    int k = idx & (KK - 1);
    int j = (idx >> 8) & (D - 1);
    int l = idx >> 15;
    float v = (k < D) ? Vw[((size_t)l * D + j) * D + k]
                      : Aw[((size_t)l * D + j) * D + (k - D)];
    W2[idx] = f2b(v);
}

// convert x fp32 -> hb bf16, fused column-sum partials -> ro0 (fp32 atomics)
__global__ void k_cvt_rsum(const float* __restrict__ x, ushort* __restrict__ hb,
                           float* __restrict__ ro0) {
    int col = threadIdx.x;  // 128
    int r0 = blockIdx.x * 64;
    int r1 = min(r0 + 64, NN);
    float s = 0.f;
    for (int r = r0; r < r1; r++) {
        float v = x[(size_t)r * D + col];
        s += v;
        hb[(size_t)r * D + col] = f2b(v);
    }
    atomicAdd(&ro0[col], s);
}

// rbias[j] = Vb[j]+Ab[j]+Rb[j] + sum_k ro[k]*Rw[j][k]
__global__ void k_rbias(const float* __restrict__ ro, const float* __restrict__ Rw,
                        const float* __restrict__ Vb, const float* __restrict__ Ab,
                        const float* __restrict__ Rb, float* __restrict__ rbias) {
    __shared__ float sro[D];
    int j = threadIdx.x;
    sro[j] = ro[j];
    __syncthreads();
    float r = Vb[j] + Ab[j] + Rb[j];
    for (int k = 0; k < D; k++) r += sro[k] * Rw[(size_t)j * D + k];
    rbias[j] = r;
}

// ---------------- per-layer ----------------

// one wave per node: A2[i][0:128] = h[i], A2[i][128:256] = h[i] + sum h[src]
__global__ void k_agg(const ushort* __restrict__ hb, const int* __restrict__ row_ptr,
                      const int* __restrict__ esrc, ushort* __restrict__ A2) {
    int wave = (blockIdx.x * blockDim.x + threadIdx.x) >> 6;
    int lane = threadIdx.x & 63;
    if (wave >= NPAD) return;
    uint* out = (uint*)(A2 + (size_t)wave * KK);
    if (wave >= NN) { out[lane] = 0u; out[64 + lane] = 0u; return; }
    const uint* hrow = (const uint*)(hb + (size_t)wave * D);
    uint su = hrow[lane];
    float ax = blo(su), ay = bhi(su);
    int b = row_ptr[wave], e2 = row_ptr[wave + 1];
    int e = b;
    float a0x = 0, a0y = 0, a1x = 0, a1y = 0, a2x = 0, a2y = 0, a3x = 0, a3y = 0;
    for (; e + 4 <= e2; e += 4) {
        int s0 = esrc[e], s1 = esrc[e + 1], s2 = esrc[e + 2], s3 = esrc[e + 3];
        uint u0 = ((const uint*)(hb + (size_t)s0 * D))[lane];
        uint u1 = ((const uint*)(hb + (size_t)s1 * D))[lane];
        uint u2 = ((const uint*)(hb + (size_t)s2 * D))[lane];
        uint u3 = ((const uint*)(hb + (size_t)s3 * D))[lane];
        a0x += blo(u0); a0y += bhi(u0);
        a1x += blo(u1); a1y += bhi(u1);
        a2x += blo(u2); a2y += bhi(u2);
        a3x += blo(u3); a3y += bhi(u3);
    }
    for (; e < e2; e++) {
        int s = esrc[e];
        uint u = ((const uint*)(hb + (size_t)s * D))[lane];
        a0x += blo(u); a0y += bhi(u);
    }
    ax += (a0x + a1x) + (a2x + a3x);
    ay += (a0y + a1y) + (a2y + a3y);
    out[lane] = su;  // exact self bits
    out[64 + lane] = (uint)f2b(ax) | ((uint)f2b(ay) << 16);
}

// hb[NPADx128] = relu(A2[NPADx256] @ W2[128x256]^T + rbias), bf16 MFMA.
// Block = 4 waves x 32 nodes = 128 nodes, all 128 cols. Fused colsum -> ro_next.
__global__ void __launch_bounds__(256) k_gemm(const ushort* __restrict__ A2,
                                              const ushort* __restrict__ W2,
                                              const float* __restrict__ rbias,
                                              ushort* __restrict__ hout,
                                              float* __restrict__ ro_next) {
    __shared__ ushort tile[4][32 * LDSW];
    __shared__ float scol[D];
    int t = threadIdx.x;
    if (t < D) scol[t] = 0.f;
    __syncthreads();

    int wave = t >> 6, lane = t & 63;
    int m = lane & 15, q = lane >> 4;
    int node0 = blockIdx.x * 128 + wave * 32;

    f32x4 acc[2][8];
#pragma unroll
    for (int a = 0; a < 2; a++)
#pragma unroll
        for (int j = 0; j < 8; j++) acc[a][j] = (f32x4){0.f, 0.f, 0.f, 0.f};

    const ushort* arow0 = A2 + (size_t)(node0 + m) * KK + q * 8;
    const ushort* arow1 = arow0 + 16 * KK;
    const ushort* brow = W2 + (size_t)m * KK + q * 8;
#pragma unroll
    for (int kt = 0; kt < 8; kt++) {
        int k0 = kt * 32;
        bf16x8 a0 = *(const bf16x8*)(arow0 + k0);
        bf16x8 a1 = *(const bf16x8*)(arow1 + k0);
#pragma unroll
        for (int j = 0; j < 8; j++) {
            bf16x8 b = *(const bf16x8*)(brow + (size_t)j * 16 * KK + k0);
            acc[0][j] = __builtin_amdgcn_mfma_f32_16x16x32_bf16(a0, b, acc[0][j], 0, 0, 0);
            acc[1][j] = __builtin_amdgcn_mfma_f32_16x16x32_bf16(a1, b, acc[1][j], 0, 0, 0);
        }
    }

    // epilogue: +rbias, relu, colsum partials, LDS transpose
    float rb[8];
#pragma unroll
    for (int j = 0; j < 8; j++) rb[j] = rbias[j * 16 + m];
    ushort* mytile = tile[wave];
    float psum[8] = {0, 0, 0, 0, 0, 0, 0, 0};
#pragma unroll
    for (int tt = 0; tt < 2; tt++)
#pragma unroll
        for (int j = 0; j < 8; j++) {
            f32x4 v = acc[tt][j];
#pragma unroll
            for (int r = 0; r < 4; r++) {
                int row = tt * 16 + q * 4 + r;  // C/D: col=lane&15, row=quad*4+reg
                float val = fmaxf(v[r] + rb[j], 0.f);
                if (node0 + row < NN) psum[j] += val;
                mytile[row * LDSW + j * 16 + m] = f2b(val);
            }
        }
#pragma unroll
    for (int j = 0; j < 8; j++) atomicAdd(&scol[j * 16 + m], psum[j]);

    // coalesced write-out (wave-private tile; in-wave lgkm ordering suffices)
#pragma unroll
    for (int it = 0; it < 8; it++) {
        int row = it * 4 + q;
        int grow = node0 + row;
        uint4 vv = *(const uint4*)(mytile + row * LDSW + m * 8);
        if (grow < NN) *(uint4*)(hout + (size_t)grow * D + m * 8) = vv;
    }
    __syncthreads();
    if (t < D) atomicAdd(&ro_next[t], scol[t]);
}

// out[i][o] = sigmoid(dot(h[i], out_w[o]) + out_b[o]); one wave per node
__global__ void k_out(const ushort* __restrict__ hb, const float* __restrict__ ow,
                      const float* __restrict__ ob, float* __restrict__ out) {
    int wave = (blockIdx.x * blockDim.x + threadIdx.x) >> 6;
    int lane = threadIdx.x & 63;
    if (wave >= NN) return;
    const uint* hr = (const uint*)(hb + (size_t)wave * D);
    uint u = hr[lane];
    float vx = blo(u), vy = bhi(u);
    const float2* w0 = (const float2*)(ow);
    const float2* w1 = (const float2*)(ow + D);
    float2 a0 = w0[lane], a1 = w1[lane];
    float p0 = vx * a0.x + vy * a0.y;
    float p1 = vx * a1.x + vy * a1.y;
    for (int off = 32; off; off >>= 1) {
        p0 += __shfl_xor(p0, off);
        p1 += __shfl_xor(p1, off);
    }
    if (lane == 0) {
        float l0 = p0 + ob[0];
        float l1 = p1 + ob[1];
        out[(size_t)wave * 2 + 0] = 1.f / (1.f + expf(-l0));
        out[(size_t)wave * 2 + 1] = 1.f / (1.f + expf(-l1));
    }
}

extern "C" void kernel_launch(void* const* d_in, const int* in_sizes, int n_in,
                              void* d_out, int out_size, void* d_ws, size_t ws_size,
                              hipStream_t stream) {
    const float* x   = (const float*)d_in[0];
    const int*   src = (const int*)d_in[1];
    const int*   dst = (const int*)d_in[2];
    const float* Vw  = (const float*)d_in[3];
    const float* Vb  = (const float*)d_in[4];
    const float* Aw  = (const float*)d_in[5];
    const float* Ab  = (const float*)d_in[6];
    const float* Rw  = (const float*)d_in[7];
    const float* Rb  = (const float*)d_in[8];
    const float* ow  = (const float*)d_in[9];
    const float* ob  = (const float*)d_in[10];
    float* out = (float*)d_out;

    char* w = (char*)d_ws;
    ushort* A2     = (ushort*)w; w += (size_t)NPAD * KK * 2;    // 25.6 MB
    ushort* hb     = (ushort*)w; w += (size_t)NPAD * D * 2;     // 12.8 MB
    ushort* W2     = (ushort*)w; w += (size_t)3 * D * KK * 2;   // 192 KB
    float*  ro     = (float*)w;  w += (size_t)4 * D * 4;        // ro[0..3][128] (zeroed)
    int*    bcnt   = (int*)w;    w += (size_t)256 * 4;          // (zeroed, contiguous w/ ro)
    int*    boff   = (int*)w;    w += (size_t)(NBUCK + 4) * 4;
    int*    bfill  = (int*)w;    w += (size_t)256 * 4;
    uint*   packed = (uint*)w;   w += (size_t)NE * 4;
    int*    esrc   = (int*)w;    w += (size_t)NE * 4;
    int*    row_ptr= (int*)w;    w += (size_t)(NN + 4) * 4;
    float*  rbias  = (float*)w;  w += (size_t)D * 4;

    // zero ro (512 floats) + bcnt (256 ints), contiguous
    k_zero_i<<<3, 256, 0, stream>>>((int*)ro, 4 * D + 256);
    k_bhist<<<EBLKS, 256, 0, stream>>>(dst, bcnt);
    k_bscan<<<1, 256, 0, stream>>>(bcnt, boff, bfill);
    k_bscat<<<EBLKS, 256, 0, stream>>>(src, dst, bfill, packed);
    k_bcsr<<<NBUCK, 256, 0, stream>>>(packed, boff, esrc, row_ptr);
    k_packw<<<(3 * D * KK + 255) / 256, 256, 0, stream>>>(Vw, Aw, W2);
    k_cvt_rsum<<<(NN + 63) / 64, D, 0, stream>>>(x, hb, ro);

    for (int l = 0; l < 3; l++) {
        k_rbias<<<1, D, 0, stream>>>(ro + (size_t)l * D, Rw + (size_t)l * D * D,
                                     Vb + (size_t)l * D, Ab + (size_t)l * D,
                                     Rb + (size_t)l * D, rbias);
        k_agg<<<NPAD / 4, 256, 0, stream>>>(hb, row_ptr, esrc, A2);
        k_gemm<<<NPAD / 128, 256, 0, stream>>>(A2, W2 + (size_t)l * D * KK, rbias, hb,
                                               ro + (size_t)(l + 1) * D);
    }
    k_out<<<(NN * 64 + 255) / 256, 256, 0, stream>>>(hb, ow, ob, out);
}

// Round 5
// 390.963 us; speedup vs baseline: 2.7963x; 1.0540x over previous
//
#include <hip/hip_runtime.h>
#include <cstdint>
#include <cstddef>

#define NN 50000
#define NE 800000
#define D 128
#define KK 256          // concat K dim: [h | agg]
#define NPAD 50048      // 391 * 128
#define LDSW 136        // tile row stride (bf16 elems): 272 B, 16B-aligned
#define NBUCK 196       // ceil(50000/256) coarse dst buckets (256 nodes each)
#define ECH 8192        // edges per block in bucket passes
#define EBLKS ((NE + ECH - 1) / ECH)  // 98
#define CVT_BLOCKS 391

typedef __bf16 bf16x8 __attribute__((ext_vector_type(8)));
typedef float f32x4 __attribute__((ext_vector_type(4)));
typedef unsigned short ushort;
typedef unsigned int uint;

__device__ __forceinline__ ushort f2b(float f) {
    uint u = __float_as_uint(f);
    uint r = (u + 0x7fffu + ((u >> 16) & 1u)) >> 16;
    return (ushort)r;
}
__device__ __forceinline__ float blo(uint u) { return __uint_as_float(u << 16); }
__device__ __forceinline__ float bhi(uint u) { return __uint_as_float(u & 0xffff0000u); }

// ---------------- CSR build (two-level bucket) ----------------

__global__ void k_zero_i(int* __restrict__ p, int n) {
    int i = blockIdx.x * blockDim.x + threadIdx.x;
    if (i < n) p[i] = 0;
}

// coarse histogram over 196 buckets, LDS-aggregated
__global__ void k_bhist(const int* __restrict__ dst, int* __restrict__ bcnt) {
    __shared__ int cnt[NBUCK];
    int t = threadIdx.x;
    if (t < NBUCK) cnt[t] = 0;
    __syncthreads();
    int e0 = blockIdx.x * ECH, e1 = min(e0 + ECH, NE);
    for (int e = e0 + t; e < e1; e += 256) atomicAdd(&cnt[dst[e] >> 8], 1);
    __syncthreads();
    if (t < NBUCK && cnt[t]) atomicAdd(&bcnt[t], cnt[t]);
}

// single block: exclusive scan of bucket counts -> boff[0..NBUCK], init bfill
__global__ void k_bscan(const int* __restrict__ bcnt, int* __restrict__ boff,
                        int* __restrict__ bfill) {
    __shared__ int s[256];
    int t = threadIdx.x;
    int v = (t < NBUCK) ? bcnt[t] : 0;
    s[t] = v;
    __syncthreads();
    for (int off = 1; off < 256; off <<= 1) {
        int u = (t >= off) ? s[t - off] : 0;
        __syncthreads();
        s[t] += u;
        __syncthreads();
    }
    int excl = s[t] - v;
    if (t < NBUCK) { boff[t] = excl; bfill[t] = excl; }
    if (t == 255) boff[NBUCK] = s[255];  // = NE
}

// scatter packed edges (src | (dst&255)<<16) into bucket-grouped runs.
__global__ void k_bscat(const int* __restrict__ src, const int* __restrict__ dst,
                        int* __restrict__ bfill, uint* __restrict__ packed) {
    __shared__ int cnt[NBUCK];
    __shared__ int base[NBUCK];
    int t = threadIdx.x;
    if (t < NBUCK) cnt[t] = 0;
    __syncthreads();
    int e0 = blockIdx.x * ECH, e1 = min(e0 + ECH, NE);
    for (int e = e0 + t; e < e1; e += 256) atomicAdd(&cnt[dst[e] >> 8], 1);
    __syncthreads();
    if (t < NBUCK) base[t] = cnt[t] ? atomicAdd(&bfill[t], cnt[t]) : 0;
    __syncthreads();
    for (int e = e0 + t; e < e1; e += 256) {
        int d = dst[e];
        int b = d >> 8;
        int p = atomicAdd(&base[b], 1);
        packed[p] = (uint)src[e] | ((uint)(d & 255) << 16);  // src < 2^16
    }
}

// one block per bucket: fine 256-bin hist + scan -> row_ptr + esrc scatter
__global__ void k_bcsr(const uint* __restrict__ packed, const int* __restrict__ boff,
                       int* __restrict__ esrc, int* __restrict__ row_ptr) {
    __shared__ int hist[256];
    __shared__ int sc[256];
    __shared__ int fill[256];
    int b = blockIdx.x, t = threadIdx.x;
    int lo = boff[b], hi = boff[b + 1], cnt = hi - lo;
    hist[t] = 0;
    __syncthreads();
    for (int i = t; i < cnt; i += 256) atomicAdd(&hist[packed[lo + i] >> 16], 1);
    __syncthreads();
    int v = hist[t];
    sc[t] = v;
    __syncthreads();
    for (int off = 1; off < 256; off <<= 1) {
        int u = (t >= off) ? sc[t - off] : 0;
        __syncthreads();
        sc[t] += u;
        __syncthreads();
    }
    int excl = sc[t] - v;
    int node = b * 256 + t;
    if (node <= NN) row_ptr[node] = lo + excl;
    fill[t] = lo + excl;
    __syncthreads();
    for (int i = t; i < cnt; i += 256) {
        uint p = packed[lo + i];
        int pos = atomicAdd(&fill[p >> 16], 1);
        esrc[pos] = (int)(p & 0xffffu);
    }
}

// ---------------- weights / readout ----------------

// pack W2b[l][j][0:128]=Vw[l][j][:], W2b[l][j][128:256]=Aw[l][j][:]  (bf16)
__global__ void k_packw(const float* __restrict__ Vw, const float* __restrict__ Aw,
                        ushort* __restrict__ W2) {
    int idx = blockIdx.x * blockDim.x + threadIdx.x;
    if (idx >= 3 * D * KK) return;
    int k = idx & (KK - 1);
    int j = (idx >> 8) & (D - 1);
    int l = idx >> 15;
    float v = (k < D) ? Vw[((size_t)l * D + j) * D + k]
                      : Aw[((size_t)l * D + j) * D + (k - D)];
    W2[idx] = f2b(v);
}

// streaming convert x fp32 -> hb bf16 (float4 in, uint2 out) + fused colsum.
// 391 blocks x 256 threads x 16 iters of float4 = 50048x128 elems (bounds-checked).
// float4-index stride is a multiple of 32 -> each thread owns 4 fixed columns.
__global__ void __launch_bounds__(256) k_cvt_rsum(const float* __restrict__ x,
                                                  ushort* __restrict__ hb,
                                                  float* __restrict__ ro0) {
    __shared__ float scol[D];
    int t = threadIdx.x;
    if (t < D) scol[t] = 0.f;
    __syncthreads();
    const float4* x4 = (const float4*)x;
    uint2* h4 = (uint2*)hb;
    float c0 = 0.f, c1 = 0.f, c2 = 0.f, c3 = 0.f;
    int base = blockIdx.x * 4096 + t;
#pragma unroll
    for (int i = 0; i < 16; i++) {
        int idx = base + i * 256;
        if (idx < NN * D / 4) {
            float4 v = x4[idx];
            c0 += v.x; c1 += v.y; c2 += v.z; c3 += v.w;
            uint2 o;
            o.x = (uint)f2b(v.x) | ((uint)f2b(v.y) << 16);
            o.y = (uint)f2b(v.z) | ((uint)f2b(v.w) << 16);
            h4[idx] = o;
        }
    }
    // lanes l and l+32 share the same column group c = t&31
    c0 += __shfl_xor(c0, 32);
    c1 += __shfl_xor(c1, 32);
    c2 += __shfl_xor(c2, 32);
    c3 += __shfl_xor(c3, 32);
    if ((t & 32) == 0) {
        int c = t & 31;
        atomicAdd(&scol[c * 4 + 0], c0);
        atomicAdd(&scol[c * 4 + 1], c1);
        atomicAdd(&scol[c * 4 + 2], c2);
        atomicAdd(&scol[c * 4 + 3], c3);
    }
    __syncthreads();
    if (t < D) atomicAdd(&ro0[t], scol[t]);
}

// rbias[j] = Vb[j]+Ab[j]+Rb[j] + sum_k ro[k]*Rw[j][k]
__global__ void k_rbias(const float* __restrict__ ro, const float* __restrict__ Rw,
                        const float* __restrict__ Vb, const float* __restrict__ Ab,
                        const float* __restrict__ Rb, float* __restrict__ rbias) {
    __shared__ float sro[D];
    int j = threadIdx.x;
    sro[j] = ro[j];
    __syncthreads();
    float r = Vb[j] + Ab[j] + Rb[j];
    for (int k = 0; k < D; k++) r += sro[k] * Rw[(size_t)j * D + k];
    rbias[j] = r;
}

// ---------------- per-layer ----------------

// one wave per node: A2[i][0:128] = h[i], A2[i][128:256] = h[i] + sum h[src]
// unroll-8 edge gather: 8 outstanding row loads per wave.
__global__ void k_agg(const ushort* __restrict__ hb, const int* __restrict__ row_ptr,
                      const int* __restrict__ esrc, ushort* __restrict__ A2) {
    int wave = (blockIdx.x * blockDim.x + threadIdx.x) >> 6;
    int lane = threadIdx.x & 63;
    if (wave >= NPAD) return;
    uint* out = (uint*)(A2 + (size_t)wave * KK);
    if (wave >= NN) { out[lane] = 0u; out[64 + lane] = 0u; return; }
    const uint* hrow = (const uint*)(hb + (size_t)wave * D);
    uint su = hrow[lane];
    float ax = blo(su), ay = bhi(su);
    int b = row_ptr[wave], e2 = row_ptr[wave + 1];
    int e = b;
    float sx[8] = {0, 0, 0, 0, 0, 0, 0, 0};
    float sy[8] = {0, 0, 0, 0, 0, 0, 0, 0};
    for (; e + 8 <= e2; e += 8) {
        uint u[8];
#pragma unroll
        for (int i = 0; i < 8; i++) {
            int s = esrc[e + i];
            u[i] = ((const uint*)(hb + (size_t)s * D))[lane];
        }
#pragma unroll
        for (int i = 0; i < 8; i++) { sx[i] += blo(u[i]); sy[i] += bhi(u[i]); }
    }
    for (; e < e2; e++) {
        int s = esrc[e];
        uint u = ((const uint*)(hb + (size_t)s * D))[lane];
        sx[0] += blo(u); sy[0] += bhi(u);
    }
    ax += ((sx[0] + sx[1]) + (sx[2] + sx[3])) + ((sx[4] + sx[5]) + (sx[6] + sx[7]));
    ay += ((sy[0] + sy[1]) + (sy[2] + sy[3])) + ((sy[4] + sy[5]) + (sy[6] + sy[7]));
    out[lane] = su;  // exact self bits
    out[64 + lane] = (uint)f2b(ax) | ((uint)f2b(ay) << 16);
}

// hb[NPADx128] = relu(A2[NPADx256] @ W2[128x256]^T + rbias), bf16 MFMA.
__global__ void __launch_bounds__(256) k_gemm(const ushort* __restrict__ A2,
                                              const ushort* __restrict__ W2,
                                              const float* __restrict__ rbias,
                                              ushort* __restrict__ hout,
                                              float* __restrict__ ro_next) {
    __shared__ ushort tile[4][32 * LDSW];
    __shared__ float scol[D];
    int t = threadIdx.x;
    if (t < D) scol[t] = 0.f;
    __syncthreads();

    int wave = t >> 6, lane = t & 63;
    int m = lane & 15, q = lane >> 4;
    int node0 = blockIdx.x * 128 + wave * 32;

    f32x4 acc[2][8];
#pragma unroll
    for (int a = 0; a < 2; a++)
#pragma unroll
        for (int j = 0; j < 8; j++) acc[a][j] = (f32x4){0.f, 0.f, 0.f, 0.f};

    const ushort* arow0 = A2 + (size_t)(node0 + m) * KK + q * 8;
    const ushort* arow1 = arow0 + 16 * KK;
    const ushort* brow = W2 + (size_t)m * KK + q * 8;
#pragma unroll
    for (int kt = 0; kt < 8; kt++) {
        int k0 = kt * 32;
        bf16x8 a0 = *(const bf16x8*)(arow0 + k0);
        bf16x8 a1 = *(const bf16x8*)(arow1 + k0);
#pragma unroll
        for (int j = 0; j < 8; j++) {
            bf16x8 b = *(const bf16x8*)(brow + (size_t)j * 16 * KK + k0);
            acc[0][j] = __builtin_amdgcn_mfma_f32_16x16x32_bf16(a0, b, acc[0][j], 0, 0, 0);
            acc[1][j] = __builtin_amdgcn_mfma_f32_16x16x32_bf16(a1, b, acc[1][j], 0, 0, 0);
        }
    }

    // epilogue: +rbias, relu, colsum partials, LDS transpose
    float rb[8];
#pragma unroll
    for (int j = 0; j < 8; j++) rb[j] = rbias[j * 16 + m];
    ushort* mytile = tile[wave];
    float psum[8] = {0, 0, 0, 0, 0, 0, 0, 0};
#pragma unroll
    for (int tt = 0; tt < 2; tt++)
#pragma unroll
        for (int j = 0; j < 8; j++) {
            f32x4 v = acc[tt][j];
#pragma unroll
            for (int r = 0; r < 4; r++) {
                int row = tt * 16 + q * 4 + r;  // C/D: col=lane&15, row=quad*4+reg
                float val = fmaxf(v[r] + rb[j], 0.f);
                if (node0 + row < NN) psum[j] += val;
                mytile[row * LDSW + j * 16 + m] = f2b(val);
            }
        }
#pragma unroll
    for (int j = 0; j < 8; j++) atomicAdd(&scol[j * 16 + m], psum[j]);

    // coalesced write-out (wave-private tile; in-wave lgkm ordering suffices)
#pragma unroll
    for (int it = 0; it < 8; it++) {
        int row = it * 4 + q;
        int grow = node0 + row;
        uint4 vv = *(const uint4*)(mytile + row * LDSW + m * 8);
        if (grow < NN) *(uint4*)(hout + (size_t)grow * D + m * 8) = vv;
    }
    __syncthreads();
    if (t < D) atomicAdd(&ro_next[t], scol[t]);
}

// out[i][o] = sigmoid(dot(h[i], out_w[o]) + out_b[o]); one wave per node
__global__ void k_out(const ushort* __restrict__ hb, const float* __restrict__ ow,
                      const float* __restrict__ ob, float* __restrict__ out) {
    int wave = (blockIdx.x * blockDim.x + threadIdx.x) >> 6;
    int lane = threadIdx.x & 63;
    if (wave >= NN) return;
    const uint* hr = (const uint*)(hb + (size_t)wave * D);
    uint u = hr[lane];
    float vx = blo(u), vy = bhi(u);
    const float2* w0 = (const float2*)(ow);
    const float2* w1 = (const float2*)(ow + D);
    float2 a0 = w0[lane], a1 = w1[lane];
    float p0 = vx * a0.x + vy * a0.y;
    float p1 = vx * a1.x + vy * a1.y;
    for (int off = 32; off; off >>= 1) {
        p0 += __shfl_xor(p0, off);
        p1 += __shfl_xor(p1, off);
    }
    if (lane == 0) {
        float l0 = p0 + ob[0];
        float l1 = p1 + ob[1];
        out[(size_t)wave * 2 + 0] = 1.f / (1.f + expf(-l0));
        out[(size_t)wave * 2 + 1] = 1.f / (1.f + expf(-l1));
    }
}

extern "C" void kernel_launch(void* const* d_in, const int* in_sizes, int n_in,
                              void* d_out, int out_size, void* d_ws, size_t ws_size,
                              hipStream_t stream) {
    const float* x   = (const float*)d_in[0];
    const int*   src = (const int*)d_in[1];
    const int*   dst = (const int*)d_in[2];
    const float* Vw  = (const float*)d_in[3];
    const float* Vb  = (const float*)d_in[4];
    const float* Aw  = (const float*)d_in[5];
    const float* Ab  = (const float*)d_in[6];
    const float* Rw  = (const float*)d_in[7];
    const float* Rb  = (const float*)d_in[8];
    const float* ow  = (const float*)d_in[9];
    const float* ob  = (const float*)d_in[10];
    float* out = (float*)d_out;

    char* w = (char*)d_ws;
    ushort* A2     = (ushort*)w; w += (size_t)NPAD * KK * 2;    // 25.6 MB
    ushort* hb     = (ushort*)w; w += (size_t)NPAD * D * 2;     // 12.8 MB
    ushort* W2     = (ushort*)w; w += (size_t)3 * D * KK * 2;   // 192 KB
    float*  ro     = (float*)w;  w += (size_t)4 * D * 4;        // ro[0..3][128] (zeroed)
    int*    bcnt   = (int*)w;    w += (size_t)256 * 4;          // (zeroed, contiguous w/ ro)
    int*    boff   = (int*)w;    w += (size_t)(NBUCK + 4) * 4;
    int*    bfill  = (int*)w;    w += (size_t)256 * 4;
    uint*   packed = (uint*)w;   w += (size_t)NE * 4;
    int*    esrc   = (int*)w;    w += (size_t)NE * 4;
    int*    row_ptr= (int*)w;    w += (size_t)(NN + 4) * 4;
    float*  rbias  = (float*)w;  w += (size_t)D * 4;

    // zero ro (512 floats) + bcnt (256 ints), contiguous
    k_zero_i<<<3, 256, 0, stream>>>((int*)ro, 4 * D + 256);
    k_bhist<<<EBLKS, 256, 0, stream>>>(dst, bcnt);
    k_bscan<<<1, 256, 0, stream>>>(bcnt, boff, bfill);
    k_bscat<<<EBLKS, 256, 0, stream>>>(src, dst, bfill, packed);
    k_bcsr<<<NBUCK, 256, 0, stream>>>(packed, boff, esrc, row_ptr);
    k_packw<<<(3 * D * KK + 255) / 256, 256, 0, stream>>>(Vw, Aw, W2);
    k_cvt_rsum<<<CVT_BLOCKS, 256, 0, stream>>>(x, hb, ro);

    for (int l = 0; l < 3; l++) {
        k_rbias<<<1, D, 0, stream>>>(ro + (size_t)l * D, Rw + (size_t)l * D * D,
                                     Vb + (size_t)l * D, Ab + (size_t)l * D,
                                     Rb + (size_t)l * D, rbias);
        k_agg<<<NPAD / 4, 256, 0, stream>>>(hb, row_ptr, esrc, A2);
        k_gemm<<<NPAD / 128, 256, 0, stream>>>(A2, W2 + (size_t)l * D * KK, rbias, hb,
                                               ro + (size_t)(l + 1) * D);
    }
    k_out<<<(NN * 64 + 255) / 256, 256, 0, stream>>>(hb, ow, ob, out);
}